// Round 1
// 565.374 us; speedup vs baseline: 1.0699x; 1.0699x over previous
//
#include <hip/hip_runtime.h>
#include <math.h>

#define NTOK  32768   // B*T
#define DDIM  2048
#define NEXP  64
#define TOPK  8
#define GAP_THR  1e-4f   // absolute logit-gap contested threshold
#define LIST_CAP 16384

// Workspace layout:
//   [0,16)          : cnt
//   [1024, 1024+512K): W fragments, bf16 hi/lo, MFMA B-frag order
//   after           : contested-token list (LIST_CAP ints)
#define WFRAG_OFF  1024
#define WFRAG_SZ   (64 * 4 * 2048)          // 64 ksteps x 4 egroups x 2KB
#define LIST_OFF   (WFRAG_OFF + WFRAG_SZ)

typedef __attribute__((ext_vector_type(8))) short s8_t;   // 8 bf16 (4 VGPR)
typedef __attribute__((ext_vector_type(4))) float f4_t;   // MFMA C/D

// round-to-nearest-even f32 -> bf16 bits
__device__ __forceinline__ unsigned short f2bf(float f) {
  const unsigned u = __builtin_bit_cast(unsigned, f);
  const unsigned r = u + 0x7FFFu + ((u >> 16) & 1u);
  return (unsigned short)(r >> 16);
}

// ---------------- W preprocessing: fp32 -> bf16 hi/lo fragments ------------
// B-frag convention for mfma_f32_16x16x32_bf16: lane holds col n = lane&15,
// k = (lane>>4)*8 + j, j=0..7. A uses the same k-slot convention, so any HW
// k-permutation cancels between operands; only C/D layout (HW-measured) binds.
// Per (kstep, egroup): 2048B block = 1024B hi frags (lane*16B) + 1024B lo.
__global__ void wprep(const float* __restrict__ w, unsigned short* __restrict__ wf,
                      int* __restrict__ cnt) {
  if (blockIdx.x == 0 && threadIdx.x == 0) cnt[0] = 0;
  const int ks   = blockIdx.x;           // 0..63  (K step of 32)
  const int eg   = threadIdx.x >> 6;     // 0..3   (expert group of 16)
  const int lane = threadIdx.x & 63;
  const int kb   = ks * 32 + ((lane >> 4) << 3);
  const int e    = (eg << 4) + (lane & 15);
  s8_t h, l;
#pragma unroll
  for (int j = 0; j < 8; ++j) {
    const float v = w[(size_t)(kb + j) * NEXP + e];
    const unsigned short hb = f2bf(v);
    const float hf = __builtin_bit_cast(float, (unsigned)hb << 16);
    h[j] = (short)hb;
    l[j] = (short)f2bf(v - hf);
  }
  unsigned short* base = wf + (size_t)(ks * 4 + eg) * 1024 + lane * 8;
  *(s8_t*)(base)       = h;
  *(s8_t*)(base + 512) = l;
}

// ---------------- main pass: bf16-split MFMA + top-9 + contested flag ------
// C = Xh*Wh + Xl*Wh + Xh*Wl  (3 MFMAs; dropped Xl*Wl ~ 3e-6 RMS on logits,
// far under GAP_THR — contested tokens go to the f64 fix pass as before).
__global__ __launch_bounds__(256, 2) void router_main(
    const float* __restrict__ x, const unsigned short* __restrict__ wf,
    float* __restrict__ out, int* __restrict__ cnt, int* __restrict__ list) {
  // logit transpose tile: 64 tokens x 64 experts, stride 68 (bank-conflict-free)
  __shared__ float llds[64 * 68];

  const int tid  = threadIdx.x;
  const int lane = tid & 63;
  const int wave = tid >> 6;
  const int col  = lane & 15;     // A row (token-within-wave) / C col (expert lo)
  const int kgrp = lane >> 4;     // k-octet group
  const int wtok = blockIdx.x * 64 + wave * 16;

  f4_t acc[4];
#pragma unroll
  for (int eg = 0; eg < 4; ++eg) acc[eg] = (f4_t){0.f, 0.f, 0.f, 0.f};

  // lane's A slice: token row (col), 8 contiguous k at kgrp*8. Two float4
  // per k-step; the 8 lanes sharing a row consume full 128B lines.
  const float* xp = x + (size_t)(wtok + col) * DDIM + (kgrp << 3);

#pragma unroll 2
  for (int ks = 0; ks < DDIM / 32; ++ks) {
    const float4 v0 = *(const float4*)(xp + ks * 32);
    const float4 v1 = *(const float4*)(xp + ks * 32 + 4);
    s8_t ah, al;
    {
      const float xv[8] = {v0.x, v0.y, v0.z, v0.w, v1.x, v1.y, v1.z, v1.w};
#pragma unroll
      for (int j = 0; j < 8; ++j) {
        const unsigned short hb = f2bf(xv[j]);
        const float hf = __builtin_bit_cast(float, (unsigned)hb << 16);
        ah[j] = (short)hb;
        al[j] = (short)f2bf(xv[j] - hf);
      }
    }
    const unsigned short* wb = wf + (size_t)ks * 4096 + lane * 8;
#pragma unroll
    for (int eg = 0; eg < 4; ++eg) {
      const s8_t bh = *(const s8_t*)(wb + eg * 1024);
      const s8_t bl = *(const s8_t*)(wb + eg * 1024 + 512);
      acc[eg] = __builtin_amdgcn_mfma_f32_16x16x32_bf16(ah, bh, acc[eg], 0, 0, 0);
      acc[eg] = __builtin_amdgcn_mfma_f32_16x16x32_bf16(al, bh, acc[eg], 0, 0, 0);
      acc[eg] = __builtin_amdgcn_mfma_f32_16x16x32_bf16(ah, bl, acc[eg], 0, 0, 0);
    }
  }

  // C/D layout (HW-measured m89/m91): col = lane&15, row = (lane>>4)*4 + reg.
  // Transpose through LDS so the epilogue can run lane=expert as before.
#pragma unroll
  for (int eg = 0; eg < 4; ++eg)
#pragma unroll
    for (int r = 0; r < 4; ++r)
      llds[(wave * 16 + kgrp * 4 + r) * 68 + eg * 16 + col] = acc[eg][r];
  __syncthreads();

  float* out_w = out;                          // (NTOK, 8) weights
  float* out_i = out + (size_t)NTOK * TOPK;    // (NTOK, 8) indices as float

#pragma unroll 1
  for (int t = 0; t < 16; ++t) {
    const int tok = wtok + t;
    const float v = llds[(wave * 16 + t) * 68 + lane];  // logit for expert `lane`

    // softmax over 64 experts
    float m = v;
#pragma unroll
    for (int off = 32; off; off >>= 1) m = fmaxf(m, __shfl_xor(m, off));
    const float ex = __expf(v - m);
    float s = ex;
#pragma unroll
    for (int off = 32; off; off >>= 1) s += __shfl_xor(s, off);
    float pw = ex / s;   // prob (selection key, knocked out as picked)
    float lw = v;        // logit (rides along for the gap check)
    int   ii = lane;

    // top-9; tie -> lower index (rank 9 only feeds the gap check)
    float selp[TOPK + 1];
    float sell[TOPK + 1];
    int   seli[TOPK + 1];
#pragma unroll
    for (int r = 0; r < TOPK + 1; ++r) {
      float bp = pw; float bl = lw; int bi = ii;
#pragma unroll
      for (int off = 32; off; off >>= 1) {
        const float op = __shfl_xor(bp, off);
        const float ol = __shfl_xor(bl, off);
        const int   oi = __shfl_xor(bi, off);
        const bool take = (op > bp) || (op == bp && oi < bi);
        bp = take ? op : bp;
        bl = take ? ol : bl;
        bi = take ? oi : bi;
      }
      selp[r] = bp; sell[r] = bl; seli[r] = bi;
      if (lane == bi) pw = -__builtin_inff();
    }

    bool contested = false;
#pragma unroll
    for (int k = 0; k < TOPK; ++k)
      contested |= (sell[k] - sell[k + 1]) <= GAP_THR;

    // commit fp32 result for every token (contested ones overwritten later)
    const float mm = selp[0];
    float ssum = 0.0f;
#pragma unroll
    for (int k = 0; k < TOPK; ++k) ssum += __expf(selp[k] - mm);
    float myv = selp[0];
    int   myi = seli[0];
#pragma unroll
    for (int k = 1; k < TOPK; ++k)
      if (lane == k) { myv = selp[k]; myi = seli[k]; }
    if (lane < TOPK) {
      out_w[(size_t)tok * TOPK + lane] = __expf(myv - mm) / ssum;
      out_i[(size_t)tok * TOPK + lane] = (float)myi;
    }

    if (contested && lane == 0) {
      const int idx = atomicAdd(cnt, 1);
      if (idx < LIST_CAP) list[idx] = tok;
    }
  }
}

// ---------------- fix pass: f64 recompute of contested tokens --------------
__global__ __launch_bounds__(256, 1) void router_fix(
    const float* __restrict__ x, const float* __restrict__ w,
    float* __restrict__ out, const int* __restrict__ cnt,
    const int* __restrict__ list) {
  const int lane = threadIdx.x & 63;
  const int wave = threadIdx.x >> 6;
  const int gw   = blockIdx.x * 4 + wave;
  const int NW   = gridDim.x * 4;

  int n = cnt[0];
  if (n > LIST_CAP) n = LIST_CAP;

  float* out_w = out;
  float* out_i = out + (size_t)NTOK * TOPK;

  for (int i = gw; i < n; i += NW) {
    const int tok = list[i];
    const float* xr = x + (size_t)tok * DDIM;
    double a0 = 0.0, a1 = 0.0, a2 = 0.0, a3 = 0.0;  // 4 indep chains
#pragma unroll 4
    for (int d4 = 0; d4 < DDIM / 4; ++d4) {
      const float4 xv = *(const float4*)(xr + d4 * 4);
      const int r = d4 * 4;
      a0 = fma((double)xv.x, (double)w[(r + 0) * NEXP + lane], a0);
      a1 = fma((double)xv.y, (double)w[(r + 1) * NEXP + lane], a1);
      a2 = fma((double)xv.z, (double)w[(r + 2) * NEXP + lane], a2);
      a3 = fma((double)xv.w, (double)w[(r + 3) * NEXP + lane], a3);
    }
    const double a = (a0 + a1) + (a2 + a3);

    double dm = a;
#pragma unroll
    for (int off = 32; off; off >>= 1) dm = fmax(dm, __shfl_xor(dm, off));
    const double dex = exp(a - dm);
    double ds = dex;
#pragma unroll
    for (int off = 32; off; off >>= 1) ds += __shfl_xor(ds, off);
    double dpv = dex / ds;

    double dselv[TOPK];
    int    dseli[TOPK];
#pragma unroll
    for (int r = 0; r < TOPK; ++r) {
      double bv = dpv;
      int    bi = lane;
#pragma unroll
      for (int off = 32; off; off >>= 1) {
        const double ov = __shfl_xor(bv, off);
        const int    oi = __shfl_xor(bi, off);
        const bool take = (ov > bv) || (ov == bv && oi < bi);
        bv = take ? ov : bv;
        bi = take ? oi : bi;
      }
      dselv[r] = bv;
      dseli[r] = bi;
      if (lane == bi) dpv = -1.0e300;
    }
    const double dmm = dselv[0];
    double dssum = 0.0;
#pragma unroll
    for (int k = 0; k < TOPK; ++k) dssum += exp(dselv[k] - dmm);
    double myv = dselv[0];
    int    myi = dseli[0];
#pragma unroll
    for (int k = 1; k < TOPK; ++k)
      if (lane == k) { myv = dselv[k]; myi = dseli[k]; }
    if (lane < TOPK) {
      out_w[(size_t)tok * TOPK + lane] = (float)(exp(myv - dmm) / dssum);
      out_i[(size_t)tok * TOPK + lane] = (float)myi;
    }
  }
}

extern "C" void kernel_launch(void* const* d_in, const int* in_sizes, int n_in,
                              void* d_out, int out_size, void* d_ws, size_t ws_size,
                              hipStream_t stream) {
  const float* x = (const float*)d_in[0];
  const float* w = (const float*)d_in[1];
  int* cnt = (int*)d_ws;
  unsigned short* wfrag = (unsigned short*)((char*)d_ws + WFRAG_OFF);
  int* list = (int*)((char*)d_ws + LIST_OFF);

  wprep<<<dim3(64), dim3(256), 0, stream>>>(w, wfrag, cnt);
  router_main<<<dim3(NTOK / 64), dim3(256), 0, stream>>>(
      x, wfrag, (float*)d_out, cnt, list);
  router_fix<<<dim3(256), dim3(256), 0, stream>>>(
      x, w, (float*)d_out, cnt, list);
}

// Round 2
// 531.345 us; speedup vs baseline: 1.1385x; 1.0640x over previous
//
#include <hip/hip_runtime.h>
#include <math.h>

#define NTOK  32768   // B*T
#define DDIM  2048
#define NEXP  64
#define TOPK  8
#define GAP_THR  1e-4f   // absolute logit-gap contested threshold
#define LIST_CAP 16384

// Workspace layout:
//   [0,16)          : cnt
//   [1024, 1024+512K): W fragments, bf16 hi/lo, MFMA B-frag order
//   after           : contested-token list (LIST_CAP ints)
#define WFRAG_OFF  1024
#define WFRAG_SZ   (64 * 4 * 2048)          // bytes: 64 ksteps x 4 egroups x 2KB
#define LIST_OFF   (WFRAG_OFF + WFRAG_SZ)

#define CK      2                   // k-steps (of 32) per staged chunk
#define NCHUNK  (DDIM / 32 / CK)    // 32

typedef __attribute__((ext_vector_type(8))) short s8_t;   // 8 bf16 (4 VGPR)
typedef __attribute__((ext_vector_type(4))) float f4_t;   // MFMA C/D
typedef __attribute__((ext_vector_type(4))) unsigned int u4_t;

typedef const __attribute__((address_space(1))) unsigned int* as1p;
typedef __attribute__((address_space(3))) unsigned int* as3p;

// async global->LDS, 16B per lane; LDS dest = uniform base + lane*16
__device__ __forceinline__ void gl2lds16(const void* g, void* l) {
  __builtin_amdgcn_global_load_lds((as1p)g, (as3p)l, 16, 0, 0);
}

// round-to-nearest-even f32 -> bf16 bits
__device__ __forceinline__ unsigned short f2bf(float f) {
  const unsigned u = __builtin_bit_cast(unsigned, f);
  const unsigned r = u + 0x7FFFu + ((u >> 16) & 1u);
  return (unsigned short)(r >> 16);
}

// split a pair of f32 into packed bf16 {hi,lo}: hi = RNE, lo = truncated
// residual. Dropped Xl*Wl + lo-trunc error ~2^-17 per term -> logit RMS
// error ~8e-6, 12x under GAP_THR (contested tokens go to the f64 pass).
struct bfpair { unsigned hi, lo; };
__device__ __forceinline__ bfpair split2(float a, float b) {
  const unsigned ua = __builtin_bit_cast(unsigned, a);
  const unsigned ub = __builtin_bit_cast(unsigned, b);
  const unsigned ra = ua + 0x7FFFu + ((ua >> 16) & 1u);
  const unsigned rb = ub + 0x7FFFu + ((ub >> 16) & 1u);
  bfpair r;
  r.hi = (ra >> 16) | (rb & 0xFFFF0000u);
  const float fa = a - __builtin_bit_cast(float, ra & 0xFFFF0000u);
  const float fb = b - __builtin_bit_cast(float, rb & 0xFFFF0000u);
  r.lo = (__builtin_bit_cast(unsigned, fa) >> 16) |
         (__builtin_bit_cast(unsigned, fb) & 0xFFFF0000u);
  return r;
}

// ---------------- W preprocessing: fp32 -> bf16 hi/lo fragments ------------
__global__ void wprep(const float* __restrict__ w, unsigned short* __restrict__ wf,
                      int* __restrict__ cnt) {
  if (blockIdx.x == 0 && threadIdx.x == 0) cnt[0] = 0;
  const int ks   = blockIdx.x;           // 0..63  (K step of 32)
  const int eg   = threadIdx.x >> 6;     // 0..3   (expert group of 16)
  const int lane = threadIdx.x & 63;
  const int kb   = ks * 32 + ((lane >> 4) << 3);
  const int e    = (eg << 4) + (lane & 15);
  s8_t h, l;
#pragma unroll
  for (int j = 0; j < 8; ++j) {
    const float v = w[(size_t)(kb + j) * NEXP + e];
    const unsigned short hb = f2bf(v);
    const float hf = __builtin_bit_cast(float, (unsigned)hb << 16);
    h[j] = (short)hb;
    l[j] = (short)f2bf(v - hf);
  }
  unsigned short* base = wf + (size_t)(ks * 4 + eg) * 1024 + lane * 8;
  *(s8_t*)(base)       = h;
  *(s8_t*)(base + 512) = l;
}

// ---------------- main pass: LDS-pipelined bf16-split MFMA -----------------
// 2-phase double-buffer: STAGE(chunk c+1) async -> COMPUTE(chunk c) from LDS
// -> __syncthreads (vmcnt drain). 64KB LDS/block, 2 blocks/CU.
__global__ __launch_bounds__(256, 2) void router_main(
    const float* __restrict__ x, const unsigned short* __restrict__ wfg,
    float* __restrict__ out, int* __restrict__ cnt, int* __restrict__ list) {
  __shared__ union {
    struct {
      float xb[2][4][CK * 512];          // [buf][wave][ks*512] : 2KB/wave/ks
      unsigned short wb[2][CK * 4096];   // [buf][ks*4096 shorts] : 8KB/ks
    } s;                                 // 64 KB total
    float ll[64 * 68];                   // epilogue transpose tile (aliased)
  } u;

  const int tid  = threadIdx.x;
  const int lane = tid & 63;
  const int wave = tid >> 6;
  const int col  = lane & 15;     // A row (token-within-wave) / C col (expert lo)
  const int kgrp = lane >> 4;     // k-octet group
  const int wtok = blockIdx.x * 64 + wave * 16;

  f4_t acc[4];
#pragma unroll
  for (int eg = 0; eg < 4; ++eg) acc[eg] = (f4_t){0.f, 0.f, 0.f, 0.f};

  // lane's x slice base: token row (col), 8 contiguous k at kgrp*8
  const float* gx0 = x + (size_t)(wtok + col) * DDIM + (kgrp << 3);

  // prologue: stage chunk 0 into buf 0
  {
    float* lx = &u.s.xb[0][wave][0];
#pragma unroll
    for (int kk = 0; kk < CK; ++kk) {
      gl2lds16(gx0 + kk * 32,     lx + kk * 512);        // lane -> lane*16
      gl2lds16(gx0 + kk * 32 + 4, lx + kk * 512 + 256);
    }
    const unsigned short* gw = wfg + wave * 2048 + lane * 8;
    unsigned short* lw = &u.s.wb[0][wave * 2048];
#pragma unroll
    for (int j = 0; j < 4; ++j)
      gl2lds16(gw + j * 512, lw + j * 512);              // linear copy
  }
  __syncthreads();   // drains vmcnt(0): chunk 0 resident

#pragma unroll 1
  for (int c = 0; c < NCHUNK; ++c) {
    const int b = c & 1;
    // STAGE chunk c+1 into the other buffer (async, in flight during compute)
    if (c + 1 < NCHUNK) {
      const int nb = b ^ 1;
      const float* gx = gx0 + (size_t)((c + 1) * CK) * 32;
      float* lx = &u.s.xb[nb][wave][0];
#pragma unroll
      for (int kk = 0; kk < CK; ++kk) {
        gl2lds16(gx + kk * 32,     lx + kk * 512);
        gl2lds16(gx + kk * 32 + 4, lx + kk * 512 + 256);
      }
      const unsigned short* gw =
          wfg + (size_t)((c + 1) * CK) * 4096 + wave * 2048 + lane * 8;
      unsigned short* lw = &u.s.wb[nb][wave * 2048];
#pragma unroll
      for (int j = 0; j < 4; ++j)
        gl2lds16(gw + j * 512, lw + j * 512);
    }

    // COMPUTE chunk c from LDS
    const float* lx = &u.s.xb[b][wave][0];
    const unsigned short* lw = &u.s.wb[b][0];
#pragma unroll
    for (int kk = 0; kk < CK; ++kk) {
      const float4 v0 = *(const float4*)(lx + kk * 512 + lane * 4);
      const float4 v1 = *(const float4*)(lx + kk * 512 + 256 + lane * 4);
      const bfpair p0 = split2(v0.x, v0.y);
      const bfpair p1 = split2(v0.z, v0.w);
      const bfpair p2 = split2(v1.x, v1.y);
      const bfpair p3 = split2(v1.z, v1.w);
      const u4_t uh = {p0.hi, p1.hi, p2.hi, p3.hi};
      const u4_t ul = {p0.lo, p1.lo, p2.lo, p3.lo};
      const s8_t ah = __builtin_bit_cast(s8_t, uh);
      const s8_t al = __builtin_bit_cast(s8_t, ul);
#pragma unroll
      for (int eg = 0; eg < 4; ++eg) {
        const s8_t bh = *(const s8_t*)(lw + kk * 4096 + eg * 1024 + lane * 8);
        const s8_t bl = *(const s8_t*)(lw + kk * 4096 + eg * 1024 + 512 + lane * 8);
        acc[eg] = __builtin_amdgcn_mfma_f32_16x16x32_bf16(ah, bh, acc[eg], 0, 0, 0);
        acc[eg] = __builtin_amdgcn_mfma_f32_16x16x32_bf16(al, bh, acc[eg], 0, 0, 0);
        acc[eg] = __builtin_amdgcn_mfma_f32_16x16x32_bf16(ah, bl, acc[eg], 0, 0, 0);
      }
    }
    __syncthreads();   // vmcnt(0)+lgkmcnt(0) drain: chunk c+1 resident, buf b free
  }

  // C/D layout (HW-measured m89/m91): col = lane&15, row = (lane>>4)*4 + reg.
  // Transpose through LDS (stride 68) so the epilogue runs lane=expert.
#pragma unroll
  for (int eg = 0; eg < 4; ++eg)
#pragma unroll
    for (int r = 0; r < 4; ++r)
      u.ll[(wave * 16 + kgrp * 4 + r) * 68 + eg * 16 + col] = acc[eg][r];
  __syncthreads();

  float* out_w = out;                          // (NTOK, 8) weights
  float* out_i = out + (size_t)NTOK * TOPK;    // (NTOK, 8) indices as float

#pragma unroll 1
  for (int t = 0; t < 16; ++t) {
    const int tok = wtok + t;
    const float v = u.ll[(wave * 16 + t) * 68 + lane];  // logit for expert `lane`

    // softmax over 64 experts
    float m = v;
#pragma unroll
    for (int off = 32; off; off >>= 1) m = fmaxf(m, __shfl_xor(m, off));
    const float ex = __expf(v - m);
    float s = ex;
#pragma unroll
    for (int off = 32; off; off >>= 1) s += __shfl_xor(s, off);
    float pw = ex / s;   // prob (selection key, knocked out as picked)
    float lw = v;        // logit (rides along for the gap check)
    int   ii = lane;

    // top-9; tie -> lower index (rank 9 only feeds the gap check)
    float selp[TOPK + 1];
    float sell[TOPK + 1];
    int   seli[TOPK + 1];
#pragma unroll
    for (int r = 0; r < TOPK + 1; ++r) {
      float bp = pw; float bl = lw; int bi = ii;
#pragma unroll
      for (int off = 32; off; off >>= 1) {
        const float op = __shfl_xor(bp, off);
        const float ol = __shfl_xor(bl, off);
        const int   oi = __shfl_xor(bi, off);
        const bool take = (op > bp) || (op == bp && oi < bi);
        bp = take ? op : bp;
        bl = take ? ol : bl;
        bi = take ? oi : bi;
      }
      selp[r] = bp; sell[r] = bl; seli[r] = bi;
      if (lane == bi) pw = -__builtin_inff();
    }

    bool contested = false;
#pragma unroll
    for (int k = 0; k < TOPK; ++k)
      contested |= (sell[k] - sell[k + 1]) <= GAP_THR;

    // commit fp32 result for every token (contested ones overwritten later)
    const float mm = selp[0];
    float ssum = 0.0f;
#pragma unroll
    for (int k = 0; k < TOPK; ++k) ssum += __expf(selp[k] - mm);
    float myv = selp[0];
    int   myi = seli[0];
#pragma unroll
    for (int k = 1; k < TOPK; ++k)
      if (lane == k) { myv = selp[k]; myi = seli[k]; }
    if (lane < TOPK) {
      out_w[(size_t)tok * TOPK + lane] = __expf(myv - mm) / ssum;
      out_i[(size_t)tok * TOPK + lane] = (float)myi;
    }

    if (contested && lane == 0) {
      const int idx = atomicAdd(cnt, 1);
      if (idx < LIST_CAP) list[idx] = tok;
    }
  }
}

// ---------------- fix pass: f64 recompute of contested tokens --------------
__global__ __launch_bounds__(256, 1) void router_fix(
    const float* __restrict__ x, const float* __restrict__ w,
    float* __restrict__ out, const int* __restrict__ cnt,
    const int* __restrict__ list) {
  const int lane = threadIdx.x & 63;
  const int wave = threadIdx.x >> 6;
  const int gw   = blockIdx.x * 4 + wave;
  const int NW   = gridDim.x * 4;

  int n = cnt[0];
  if (n > LIST_CAP) n = LIST_CAP;

  float* out_w = out;
  float* out_i = out + (size_t)NTOK * TOPK;

  for (int i = gw; i < n; i += NW) {
    const int tok = list[i];
    const float* xr = x + (size_t)tok * DDIM;
    double a0 = 0.0, a1 = 0.0, a2 = 0.0, a3 = 0.0;  // 4 indep chains
#pragma unroll 4
    for (int d4 = 0; d4 < DDIM / 4; ++d4) {
      const float4 xv = *(const float4*)(xr + d4 * 4);
      const int r = d4 * 4;
      a0 = fma((double)xv.x, (double)w[(r + 0) * NEXP + lane], a0);
      a1 = fma((double)xv.y, (double)w[(r + 1) * NEXP + lane], a1);
      a2 = fma((double)xv.z, (double)w[(r + 2) * NEXP + lane], a2);
      a3 = fma((double)xv.w, (double)w[(r + 3) * NEXP + lane], a3);
    }
    const double a = (a0 + a1) + (a2 + a3);

    double dm = a;
#pragma unroll
    for (int off = 32; off; off >>= 1) dm = fmax(dm, __shfl_xor(dm, off));
    const double dex = exp(a - dm);
    double ds = dex;
#pragma unroll
    for (int off = 32; off; off >>= 1) ds += __shfl_xor(ds, off);
    double dpv = dex / ds;

    double dselv[TOPK];
    int    dseli[TOPK];
#pragma unroll
    for (int r = 0; r < TOPK; ++r) {
      double bv = dpv;
      int    bi = lane;
#pragma unroll
      for (int off = 32; off; off >>= 1) {
        const double ov = __shfl_xor(bv, off);
        const int    oi = __shfl_xor(bi, off);
        const bool take = (ov > bv) || (ov == bv && oi < bi);
        bv = take ? ov : bv;
        bi = take ? oi : bi;
      }
      dselv[r] = bv;
      dseli[r] = bi;
      if (lane == bi) dpv = -1.0e300;
    }
    const double dmm = dselv[0];
    double dssum = 0.0;
#pragma unroll
    for (int k = 0; k < TOPK; ++k) dssum += exp(dselv[k] - dmm);
    double myv = dselv[0];
    int    myi = dseli[0];
#pragma unroll
    for (int k = 1; k < TOPK; ++k)
      if (lane == k) { myv = dselv[k]; myi = dseli[k]; }
    if (lane < TOPK) {
      out_w[(size_t)tok * TOPK + lane] = (float)(exp(myv - dmm) / dssum);
      out_i[(size_t)tok * TOPK + lane] = (float)myi;
    }
  }
}

extern "C" void kernel_launch(void* const* d_in, const int* in_sizes, int n_in,
                              void* d_out, int out_size, void* d_ws, size_t ws_size,
                              hipStream_t stream) {
  const float* x = (const float*)d_in[0];
  const float* w = (const float*)d_in[1];
  int* cnt = (int*)d_ws;
  unsigned short* wfrag = (unsigned short*)((char*)d_ws + WFRAG_OFF);
  int* list = (int*)((char*)d_ws + LIST_OFF);

  wprep<<<dim3(64), dim3(256), 0, stream>>>(w, wfrag, cnt);
  router_main<<<dim3(NTOK / 64), dim3(256), 0, stream>>>(
      x, wfrag, (float*)d_out, cnt, list);
  router_fix<<<dim3(256), dim3(256), 0, stream>>>(
      x, w, (float*)d_out, cnt, list);
}

// Round 3
// 529.057 us; speedup vs baseline: 1.1434x; 1.0043x over previous
//
#include <hip/hip_runtime.h>
#include <math.h>

#define NTOK  32768   // B*T
#define DDIM  2048
#define NEXP  64
#define TOPK  8
#define GAP_THR  1e-4f   // absolute logit-gap contested threshold
#define LIST_CAP 16384

// Workspace layout:
//   [0,16)          : cnt
//   [1024, 1024+512K): W fragments, bf16 hi/lo, MFMA B-frag order
//   after           : contested-token list (LIST_CAP ints)
#define WFRAG_OFF  1024
#define WFRAG_SZ   (64 * 4 * 2048)          // bytes: 64 ksteps x 4 egroups x 2KB
#define LIST_OFF   (WFRAG_OFF + WFRAG_SZ)

#define NKS   32      // k-steps (of 32) per K-half

typedef __attribute__((ext_vector_type(8))) short s8_t;   // 8 bf16 (4 VGPR)
typedef __attribute__((ext_vector_type(4))) float f4_t;   // MFMA C/D
typedef __attribute__((ext_vector_type(4))) unsigned int u4_t;

typedef const __attribute__((address_space(1))) unsigned int* as1p;
typedef __attribute__((address_space(3))) unsigned int* as3p;

// async global->LDS, 16B per lane; LDS dest = uniform base + lane*16
__device__ __forceinline__ void gl2lds16(const void* g, void* l) {
  __builtin_amdgcn_global_load_lds((as1p)g, (as3p)l, 16, 0, 0);
}

// round-to-nearest-even f32 -> bf16 bits
__device__ __forceinline__ unsigned short f2bf(float f) {
  const unsigned u = __builtin_bit_cast(unsigned, f);
  const unsigned r = u + 0x7FFFu + ((u >> 16) & 1u);
  return (unsigned short)(r >> 16);
}

// split a pair of f32 into packed bf16 {hi,lo}: hi = RNE, lo = truncated
// residual. Dropped Xl*Wl + lo-trunc error ~2^-17 per term -> logit RMS
// error ~8e-6, 12x under GAP_THR (contested tokens go to the f64 pass).
struct bfpair { unsigned hi, lo; };
__device__ __forceinline__ bfpair split2(float a, float b) {
  const unsigned ua = __builtin_bit_cast(unsigned, a);
  const unsigned ub = __builtin_bit_cast(unsigned, b);
  const unsigned ra = ua + 0x7FFFu + ((ua >> 16) & 1u);
  const unsigned rb = ub + 0x7FFFu + ((ub >> 16) & 1u);
  bfpair r;
  r.hi = (ra >> 16) | (rb & 0xFFFF0000u);
  const float fa = a - __builtin_bit_cast(float, ra & 0xFFFF0000u);
  const float fb = b - __builtin_bit_cast(float, rb & 0xFFFF0000u);
  r.lo = (__builtin_bit_cast(unsigned, fa) >> 16) |
         (__builtin_bit_cast(unsigned, fb) & 0xFFFF0000u);
  return r;
}

// ---------------- W preprocessing: fp32 -> bf16 hi/lo fragments ------------
__global__ void wprep(const float* __restrict__ w, unsigned short* __restrict__ wf,
                      int* __restrict__ cnt) {
  if (blockIdx.x == 0 && threadIdx.x == 0) cnt[0] = 0;
  const int ks   = blockIdx.x;           // 0..63  (K step of 32)
  const int eg   = threadIdx.x >> 6;     // 0..3   (expert group of 16)
  const int lane = threadIdx.x & 63;
  const int kb   = ks * 32 + ((lane >> 4) << 3);
  const int e    = (eg << 4) + (lane & 15);
  s8_t h, l;
#pragma unroll
  for (int j = 0; j < 8; ++j) {
    const float v = w[(size_t)(kb + j) * NEXP + e];
    const unsigned short hb = f2bf(v);
    const float hf = __builtin_bit_cast(float, (unsigned)hb << 16);
    h[j] = (short)hb;
    l[j] = (short)f2bf(v - hf);
  }
  unsigned short* base = wf + (size_t)(ks * 4 + eg) * 1024 + lane * 8;
  *(s8_t*)(base)       = h;
  *(s8_t*)(base + 512) = l;
}

// ---------------- main pass: K-split, counted-vmcnt pipeline ---------------
// 8 waves/block: waves 0-3 = K-half 0, waves 4-7 = K-half 1, same 64 tokens.
// Per chunk (1 k-step per half): issue(c+1) -> vmcnt(4) -> barrier ->
// compute(c) -> barrier. Loads never drain to 0 in the loop (T4).
// 64KB LDS -> 2 blocks/CU -> 16 waves/CU.
__global__ __launch_bounds__(512, 4) void router_main(
    const float* __restrict__ x, const unsigned short* __restrict__ wfg,
    float* __restrict__ out, int* __restrict__ cnt, int* __restrict__ list) {
  __shared__ union {
    struct {
      float xb[2][8][512];                // 32 KB: [buf][wave][16tok x 32k]
      unsigned short wb[2][2][4096];      // 32 KB: [buf][half][4eg x (hi|lo)]
    } s;                                  // 64 KB
    float ll[64 * 68];                    // epilogue transpose tile (aliased)
  } u;

  const int tid  = threadIdx.x;
  const int lane = tid & 63;
  const int wave = tid >> 6;      // 0..7
  const int pair = wave & 3;      // token group (16 tokens)
  const int half = wave >> 2;     // K half
  const int col  = lane & 15;     // A row (token) / C col (expert lo)
  const int kgrp = lane >> 4;     // k-octet group
  const int tok0 = blockIdx.x * 64 + pair * 16;

  f4_t acc[4];
#pragma unroll
  for (int eg = 0; eg < 4; ++eg) acc[eg] = (f4_t){0.f, 0.f, 0.f, 0.f};

  // lane's x slice base: token row (col), this K-half, octet kgrp
  const float* gx = x + (size_t)(tok0 + col) * DDIM + half * (NKS * 32) + (kgrp << 3);
  const unsigned short* gw0 = wfg + pair * 1024 + lane * 8;

  // issue chunk j of this half into buffer bb (4 async loads, 4KB/wave)
  auto issue = [&](int j, int bb) {
    gl2lds16(gx + j * 32,     &u.s.xb[bb][wave][0]);
    gl2lds16(gx + j * 32 + 4, &u.s.xb[bb][wave][256]);
    const unsigned short* g = gw0 + (size_t)(half * NKS + j) * 4096;
    gl2lds16(g,       &u.s.wb[bb][half][pair * 1024]);
    gl2lds16(g + 512, &u.s.wb[bb][half][pair * 1024 + 512]);
  };

  // compute one k-step from buffer bb (12 MFMA)
  auto compute = [&](int bb) {
    const float* lx = &u.s.xb[bb][wave][0];
    const unsigned short* lw = &u.s.wb[bb][half][0];
    const float4 v0 = *(const float4*)(lx + lane * 4);
    const float4 v1 = *(const float4*)(lx + 256 + lane * 4);
    const bfpair p0 = split2(v0.x, v0.y);
    const bfpair p1 = split2(v0.z, v0.w);
    const bfpair p2 = split2(v1.x, v1.y);
    const bfpair p3 = split2(v1.z, v1.w);
    const u4_t uh = {p0.hi, p1.hi, p2.hi, p3.hi};
    const u4_t ul = {p0.lo, p1.lo, p2.lo, p3.lo};
    const s8_t ah = __builtin_bit_cast(s8_t, uh);
    const s8_t al = __builtin_bit_cast(s8_t, ul);
#pragma unroll
    for (int eg = 0; eg < 4; ++eg) {
      const s8_t bh = *(const s8_t*)(lw + eg * 1024 + lane * 8);
      const s8_t bl = *(const s8_t*)(lw + eg * 1024 + 512 + lane * 8);
      acc[eg] = __builtin_amdgcn_mfma_f32_16x16x32_bf16(ah, bh, acc[eg], 0, 0, 0);
      acc[eg] = __builtin_amdgcn_mfma_f32_16x16x32_bf16(al, bh, acc[eg], 0, 0, 0);
      acc[eg] = __builtin_amdgcn_mfma_f32_16x16x32_bf16(ah, bl, acc[eg], 0, 0, 0);
    }
  };

  issue(0, 0);   // prologue: chunk 0 in flight

#pragma unroll 1
  for (int c = 0; c < NKS - 1; ++c) {
    issue(c + 1, (c + 1) & 1);
    // chunk c's 4 loads done; chunk c+1's 4 stay in flight (never drain to 0)
    asm volatile("s_waitcnt vmcnt(4)" ::: "memory");
    __builtin_amdgcn_s_barrier();
    asm volatile("" ::: "memory");   // no LDS reads hoisted above the barrier
    compute(c & 1);
    asm volatile("" ::: "memory");   // no LDS reads sunk below the barrier
    __builtin_amdgcn_s_barrier();
  }
  // last chunk: nothing left to issue
  asm volatile("s_waitcnt vmcnt(0)" ::: "memory");
  __builtin_amdgcn_s_barrier();
  asm volatile("" ::: "memory");
  compute((NKS - 1) & 1);
  __syncthreads();   // all computes done before ll (aliases buffers) is written

  // combine K-halves through the transpose tile.
  // C/D layout (HW-measured m89/m91): col = lane&15, row = (lane>>4)*4 + reg.
  if (half == 0) {
#pragma unroll
    for (int eg = 0; eg < 4; ++eg)
#pragma unroll
      for (int r = 0; r < 4; ++r)
        u.ll[(pair * 16 + kgrp * 4 + r) * 68 + eg * 16 + col] = acc[eg][r];
  }
  __syncthreads();
  if (half == 1) {
#pragma unroll
    for (int eg = 0; eg < 4; ++eg)
#pragma unroll
      for (int r = 0; r < 4; ++r)
        u.ll[(pair * 16 + kgrp * 4 + r) * 68 + eg * 16 + col] += acc[eg][r];
  }
  __syncthreads();

  float* out_w = out;                          // (NTOK, 8) weights
  float* out_i = out + (size_t)NTOK * TOPK;    // (NTOK, 8) indices as float

  // epilogue: 8 tokens per wave (halves split each pair's 16 tokens)
  const int trow0 = pair * 16 + half * 8;
#pragma unroll 1
  for (int t = 0; t < 8; ++t) {
    const int row = trow0 + t;
    const int tok = blockIdx.x * 64 + row;
    const float v = u.ll[row * 68 + lane];  // logit for expert `lane`

    // softmax over 64 experts
    float m = v;
#pragma unroll
    for (int off = 32; off; off >>= 1) m = fmaxf(m, __shfl_xor(m, off));
    const float ex = __expf(v - m);
    float s = ex;
#pragma unroll
    for (int off = 32; off; off >>= 1) s += __shfl_xor(s, off);
    float pw = ex / s;   // prob (selection key, knocked out as picked)
    float lw = v;        // logit (rides along for the gap check)
    int   ii = lane;

    // top-9; tie -> lower index (rank 9 only feeds the gap check)
    float selp[TOPK + 1];
    float sell[TOPK + 1];
    int   seli[TOPK + 1];
#pragma unroll
    for (int r = 0; r < TOPK + 1; ++r) {
      float bp = pw; float bl = lw; int bi = ii;
#pragma unroll
      for (int off = 32; off; off >>= 1) {
        const float op = __shfl_xor(bp, off);
        const float ol = __shfl_xor(bl, off);
        const int   oi = __shfl_xor(bi, off);
        const bool take = (op > bp) || (op == bp && oi < bi);
        bp = take ? op : bp;
        bl = take ? ol : bl;
        bi = take ? oi : bi;
      }
      selp[r] = bp; sell[r] = bl; seli[r] = bi;
      if (lane == bi) pw = -__builtin_inff();
    }

    bool contested = false;
#pragma unroll
    for (int k = 0; k < TOPK; ++k)
      contested |= (sell[k] - sell[k + 1]) <= GAP_THR;

    // commit fp32 result for every token (contested ones overwritten later)
    const float mm = selp[0];
    float ssum = 0.0f;
#pragma unroll
    for (int k = 0; k < TOPK; ++k) ssum += __expf(selp[k] - mm);
    float myv = selp[0];
    int   myi = seli[0];
#pragma unroll
    for (int k = 1; k < TOPK; ++k)
      if (lane == k) { myv = selp[k]; myi = seli[k]; }
    if (lane < TOPK) {
      out_w[(size_t)tok * TOPK + lane] = __expf(myv - mm) / ssum;
      out_i[(size_t)tok * TOPK + lane] = (float)myi;
    }

    if (contested && lane == 0) {
      const int idx = atomicAdd(cnt, 1);
      if (idx < LIST_CAP) list[idx] = tok;
    }
  }
}

// ---------------- fix pass: f64 recompute of contested tokens --------------
__global__ __launch_bounds__(256, 1) void router_fix(
    const float* __restrict__ x, const float* __restrict__ w,
    float* __restrict__ out, const int* __restrict__ cnt,
    const int* __restrict__ list) {
  const int lane = threadIdx.x & 63;
  const int wave = threadIdx.x >> 6;
  const int gw   = blockIdx.x * 4 + wave;
  const int NW   = gridDim.x * 4;

  int n = cnt[0];
  if (n > LIST_CAP) n = LIST_CAP;

  float* out_w = out;
  float* out_i = out + (size_t)NTOK * TOPK;

  for (int i = gw; i < n; i += NW) {
    const int tok = list[i];
    const float* xr = x + (size_t)tok * DDIM;
    double a0 = 0.0, a1 = 0.0, a2 = 0.0, a3 = 0.0;  // 4 indep chains
#pragma unroll 4
    for (int d4 = 0; d4 < DDIM / 4; ++d4) {
      const float4 xv = *(const float4*)(xr + d4 * 4);
      const int r = d4 * 4;
      a0 = fma((double)xv.x, (double)w[(r + 0) * NEXP + lane], a0);
      a1 = fma((double)xv.y, (double)w[(r + 1) * NEXP + lane], a1);
      a2 = fma((double)xv.z, (double)w[(r + 2) * NEXP + lane], a2);
      a3 = fma((double)xv.w, (double)w[(r + 3) * NEXP + lane], a3);
    }
    const double a = (a0 + a1) + (a2 + a3);

    double dm = a;
#pragma unroll
    for (int off = 32; off; off >>= 1) dm = fmax(dm, __shfl_xor(dm, off));
    const double dex = exp(a - dm);
    double ds = dex;
#pragma unroll
    for (int off = 32; off; off >>= 1) ds += __shfl_xor(ds, off);
    double dpv = dex / ds;

    double dselv[TOPK];
    int    dseli[TOPK];
#pragma unroll
    for (int r = 0; r < TOPK; ++r) {
      double bv = dpv;
      int    bi = lane;
#pragma unroll
      for (int off = 32; off; off >>= 1) {
        const double ov = __shfl_xor(bv, off);
        const int    oi = __shfl_xor(bi, off);
        const bool take = (ov > bv) || (ov == bv && oi < bi);
        bv = take ? ov : bv;
        bi = take ? oi : bi;
      }
      dselv[r] = bv;
      dseli[r] = bi;
      if (lane == bi) dpv = -1.0e300;
    }
    const double dmm = dselv[0];
    double dssum = 0.0;
#pragma unroll
    for (int k = 0; k < TOPK; ++k) dssum += exp(dselv[k] - dmm);
    double myv = dselv[0];
    int    myi = dseli[0];
#pragma unroll
    for (int k = 1; k < TOPK; ++k)
      if (lane == k) { myv = dselv[k]; myi = dseli[k]; }
    if (lane < TOPK) {
      out_w[(size_t)tok * TOPK + lane] = (float)(exp(myv - dmm) / dssum);
      out_i[(size_t)tok * TOPK + lane] = (float)myi;
    }
  }
}

extern "C" void kernel_launch(void* const* d_in, const int* in_sizes, int n_in,
                              void* d_out, int out_size, void* d_ws, size_t ws_size,
                              hipStream_t stream) {
  const float* x = (const float*)d_in[0];
  const float* w = (const float*)d_in[1];
  int* cnt = (int*)d_ws;
  unsigned short* wfrag = (unsigned short*)((char*)d_ws + WFRAG_OFF);
  int* list = (int*)((char*)d_ws + LIST_OFF);

  wprep<<<dim3(64), dim3(256), 0, stream>>>(w, wfrag, cnt);
  router_main<<<dim3(NTOK / 64), dim3(512), 0, stream>>>(
      x, wfrag, (float*)d_out, cnt, list);
  router_fix<<<dim3(256), dim3(256), 0, stream>>>(
      x, w, (float*)d_out, cnt, list);
}